// Round 1
// baseline (276.265 us; speedup 1.0000x reference)
//
#include <hip/hip_runtime.h>

#define DM 256
#define NNODE 128
#define NB 8

typedef __attribute__((ext_vector_type(8))) __bf16 bf16x8;
typedef __attribute__((ext_vector_type(4))) float f32x4;

__device__ __forceinline__ float siluf(float x) { return x / (1.0f + __expf(-x)); }

// ---------------- weight conversion: bf16, transposed to [out][k] ----------------
__global__ __launch_bounds__(256) void k_prep(
    const float* __restrict__ We1, const float* __restrict__ Wx1,
    const float* __restrict__ We2, const float* __restrict__ Wx2,
    __bf16* __restrict__ wt_e, __bf16* __restrict__ wt_x,
    __bf16* __restrict__ w2e, __bf16* __restrict__ w2x)
{
  int idx = blockIdx.x * 256 + threadIdx.x;   // 0..65535
  if (idx < 16384) {                          // [256 c][64 k] tails (rows 512..575)
    int c = idx >> 6, k = idx & 63;
    wt_e[idx] = (__bf16)We1[(512 + k) * 256 + c];
    wt_x[idx] = (__bf16)Wx1[(512 + k) * 256 + c];
  }
  {                                           // [256 c][256 k]
    int c = idx >> 8, k = idx & 255;
    w2e[idx] = (__bf16)We2[k * 256 + c];
    w2x[idx] = (__bf16)Wx2[k * 256 + c];
  }
}

// ---------------- node projections: hi_e(+b), hj_e, hi_x(+b), hj_x ----------------
__global__ __launch_bounds__(256) void k_nodes(
    const float* __restrict__ invf, const float* __restrict__ We1,
    const float* __restrict__ Wx1, const float* __restrict__ be1,
    const float* __restrict__ bx1,
    float* __restrict__ hie, float* __restrict__ hje,
    float* __restrict__ hix, float* __restrict__ hjx)
{
  __shared__ float sInv[4][256];
  int c = threadIdx.x;
  int node0 = blockIdx.x * 4;
  #pragma unroll
  for (int nn = 0; nn < 4; nn++)
    sInv[nn][c] = invf[(node0 + nn) * 256 + c];
  __syncthreads();
  float aie[4] = {0,0,0,0}, aje[4] = {0,0,0,0}, aix[4] = {0,0,0,0}, ajx[4] = {0,0,0,0};
  #pragma unroll 4
  for (int k = 0; k < 256; k++) {
    float wie = We1[k * 256 + c];
    float wje = We1[(256 + k) * 256 + c];
    float wix = Wx1[k * 256 + c];
    float wjx = Wx1[(256 + k) * 256 + c];
    #pragma unroll
    for (int nn = 0; nn < 4; nn++) {
      float v = sInv[nn][k];
      aie[nn] += v * wie; aje[nn] += v * wje;
      aix[nn] += v * wix; ajx[nn] += v * wjx;
    }
  }
  #pragma unroll
  for (int nn = 0; nn < 4; nn++) {
    hie[(node0 + nn) * 256 + c] = aie[nn] + be1[c];
    hje[(node0 + nn) * 256 + c] = aje[nn];
    hix[(node0 + nn) * 256 + c] = aix[nn] + bx1[c];
    hjx[(node0 + nn) * 256 + c] = ajx[nn];
  }
}

// ---------------- one edge-MLP path (shared by phi_e and phi_x) ----------------
template<bool EPATH>
__device__ __forceinline__ void egnn_path(
    int tid,
    const __bf16* sE, char* sSb,
    const float* shi, const float* slast, const float* sqv,
    const float* __restrict__ hjb,          // hj base for this b (+ j*256 + c)
    const __bf16* __restrict__ wt,          // [256][64]  (GEMM1 B, transposed)
    const __bf16* __restrict__ w2,          // [256][256] (GEMM2 B, transposed)
    const float* __restrict__ bias2,        // b_e2 / b_x2
    const float* __restrict__ vvec,         // W_att / W_x3
    float* sRed, float battb,
    float* sAttW, float* sNM,
    const float* __restrict__ adjrow,
    float* __restrict__ node_msg_out)
{
  const int lane = tid & 63;
  const int w = tid >> 6;
  const int lr = lane & 15;
  const int lg = lane >> 4;
  const int row0 = (w >> 2) * 64;
  const int col0 = (w & 3) * 64;

  // ---- GEMM1: [128 x 64] @ [64 x 256] ----
  f32x4 acc[4][4];
  #pragma unroll
  for (int m = 0; m < 4; m++)
    #pragma unroll
    for (int n = 0; n < 4; n++) { f32x4 z = {0.f,0.f,0.f,0.f}; acc[m][n] = z; }

  #pragma unroll
  for (int ks = 0; ks < 2; ks++) {
    bf16x8 af[4], bfr[4];
    #pragma unroll
    for (int m = 0; m < 4; m++)
      af[m] = *(const bf16x8*)(sE + (row0 + m * 16 + lr) * 72 + ks * 32 + lg * 8);
    #pragma unroll
    for (int n = 0; n < 4; n++)
      bfr[n] = *(const bf16x8*)(wt + (col0 + n * 16 + lr) * 64 + ks * 32 + lg * 8);
    #pragma unroll
    for (int m = 0; m < 4; m++)
      #pragma unroll
      for (int n = 0; n < 4; n++)
        acc[m][n] = __builtin_amdgcn_mfma_f32_16x16x32_bf16(af[m], bfr[n], acc[m][n], 0, 0, 0);
  }
  // epilogue: + hi[c] + hj[j][c] + sq[j]*w576[c], silu, bf16 -> swizzled LDS
  #pragma unroll
  for (int m = 0; m < 4; m++) {
    #pragma unroll
    for (int n = 0; n < 4; n++) {
      int c = col0 + n * 16 + lr;
      #pragma unroll
      for (int r = 0; r < 4; r++) {
        int j = row0 + m * 16 + lg * 4 + r;
        float v = acc[m][n][r] + shi[c] + hjb[j * 256 + c] + sqv[j] * slast[c];
        float s = siluf(v);
        int off = (j * 512 + c * 2) ^ ((j & 7) << 4);
        *(__bf16*)(sSb + off) = (__bf16)s;
      }
    }
  }
  __syncthreads();

  // ---- GEMM2: [128 x 256] @ [256 x 256] ----
  f32x4 acc2[4][4];
  #pragma unroll
  for (int m = 0; m < 4; m++)
    #pragma unroll
    for (int n = 0; n < 4; n++) { f32x4 z = {0.f,0.f,0.f,0.f}; acc2[m][n] = z; }

  for (int ks = 0; ks < 8; ks++) {
    bf16x8 af[4], bfr[4];
    #pragma unroll
    for (int m = 0; m < 4; m++) {
      int j = row0 + m * 16 + lr;
      int off = (j * 512 + (ks * 32 + lg * 8) * 2) ^ ((j & 7) << 4);
      af[m] = *(const bf16x8*)(sSb + off);
    }
    #pragma unroll
    for (int n = 0; n < 4; n++)
      bfr[n] = *(const bf16x8*)(w2 + (col0 + n * 16 + lr) * 256 + ks * 32 + lg * 8);
    #pragma unroll
    for (int m = 0; m < 4; m++)
      #pragma unroll
      for (int n = 0; n < 4; n++)
        acc2[m][n] = __builtin_amdgcn_mfma_f32_16x16x32_bf16(af[m], bfr[n], acc2[m][n], 0, 0, 0);
  }

  // silu(+bias2); per-row dot with vvec -> sRed[j]
  float vv[4], bb[4];
  #pragma unroll
  for (int n = 0; n < 4; n++) {
    vv[n] = vvec[col0 + n * 16 + lr];
    bb[n] = bias2[col0 + n * 16 + lr];
  }
  float p[4][4];
  #pragma unroll
  for (int m = 0; m < 4; m++)
    #pragma unroll
    for (int r = 0; r < 4; r++) p[m][r] = 0.f;
  #pragma unroll
  for (int m = 0; m < 4; m++)
    #pragma unroll
    for (int n = 0; n < 4; n++)
      #pragma unroll
      for (int r = 0; r < 4; r++) {
        float s = siluf(acc2[m][n][r] + bb[n]);
        acc2[m][n][r] = s;
        p[m][r] += s * vv[n];
      }
  #pragma unroll
  for (int off = 1; off < 16; off <<= 1)
    #pragma unroll
    for (int m = 0; m < 4; m++)
      #pragma unroll
      for (int r = 0; r < 4; r++)
        p[m][r] += __shfl_xor(p[m][r], off);
  if (lr == 0) {
    #pragma unroll
    for (int m = 0; m < 4; m++)
      #pragma unroll
      for (int r = 0; r < 4; r++)
        atomicAdd(&sRed[row0 + m * 16 + lg * 4 + r], p[m][r]);
  }
  __syncthreads();

  if constexpr (EPATH) {
    if (tid < 128)
      sAttW[tid] = (1.0f / (1.0f + __expf(-(sRed[tid] + battb)))) * adjrow[tid];
    __syncthreads();
    float q[4] = {0.f, 0.f, 0.f, 0.f};
    #pragma unroll
    for (int m = 0; m < 4; m++)
      #pragma unroll
      for (int r = 0; r < 4; r++) {
        float aw = sAttW[row0 + m * 16 + lg * 4 + r];
        #pragma unroll
        for (int n = 0; n < 4; n++) q[n] += acc2[m][n][r] * aw;
      }
    #pragma unroll
    for (int n = 0; n < 4; n++) {
      q[n] += __shfl_xor(q[n], 16);
      q[n] += __shfl_xor(q[n], 32);
    }
    if (lane < 16) {
      #pragma unroll
      for (int n = 0; n < 4; n++) atomicAdd(&sNM[col0 + n * 16 + lane], q[n]);
    }
    __syncthreads();
    if (tid < 256) node_msg_out[tid] = sNM[tid];
  }
}

// ---------------- main per-(b,i) edge kernel ----------------
__global__ __launch_bounds__(512, 2) void k_edge(
    const float* __restrict__ coords, const float* __restrict__ adjm,
    const float* __restrict__ amask, const float* __restrict__ ef,
    const float* __restrict__ We1, const float* __restrict__ Wx1,
    const float* __restrict__ Watt, const float* __restrict__ batt,
    const float* __restrict__ be2, const float* __restrict__ bx2,
    const float* __restrict__ bx3,
    const float* __restrict__ hie, const float* __restrict__ hje,
    const float* __restrict__ hix, const float* __restrict__ hjx,
    const __bf16* __restrict__ wt_e, const __bf16* __restrict__ wt_x,
    const __bf16* __restrict__ w2e, const __bf16* __restrict__ w2x,
    const float* __restrict__ Wx3,
    float* __restrict__ node_msg, float* __restrict__ out_coords)
{
  __shared__ __align__(16) __bf16 sE[128 * 72];
  __shared__ __align__(16) char sSb[128 * 512];
  __shared__ float shie[256], shix[256], slaste[256], slastx[256];
  __shared__ float sqv[128], sRed1[128], sRed2[128], sAttW[128], sNM[256];
  __shared__ float sRx[128], sRy[128], sRz[128];
  __shared__ float sNum;

  const int tid = threadIdx.x;
  const int blk = blockIdx.x;      // b*128 + i
  const int b = blk >> 7;

  // ---- phase 1: zero reductions, stage hi/w576, sq, E ----
  if (tid < 128) {
    sRed1[tid] = 0.f;
    sRed2[tid] = 0.f;
    if (tid == 0) sNum = 0.f;
  } else if (tid < 384) {
    sNM[tid - 128] = 0.f;
  }
  if (tid < 256) {
    shie[tid] = hie[(size_t)blk * 256 + tid];
    shix[tid] = hix[(size_t)blk * 256 + tid];
    slaste[tid] = We1[576 * 256 + tid];
    slastx[tid] = Wx1[576 * 256 + tid];
  }
  float cix = coords[blk * 3 + 0], ciy = coords[blk * 3 + 1], ciz = coords[blk * 3 + 2];
  if (tid >= 384) {
    int j = tid - 384;
    float dx = cix - coords[(b * 128 + j) * 3 + 0];
    float dy = ciy - coords[(b * 128 + j) * 3 + 1];
    float dz = ciz - coords[(b * 128 + j) * 3 + 2];
    sqv[j] = dx * dx + dy * dy + dz * dz;
  }
  const float* efb = ef + (size_t)blk * 8192;
  #pragma unroll
  for (int it = 0; it < 16; it++) {
    int idx = tid + it * 512;
    sE[(idx >> 6) * 72 + (idx & 63)] = (__bf16)efb[idx];
  }
  __syncthreads();
  if (tid >= 256 && tid < 384)
    atomicAdd(&sNum, amask[b * 128 + (tid - 256)]);   // completes well before use

  // ---- phi_e ----
  egnn_path<true>(tid, sE, sSb, shie, slaste, sqv,
                  hje + (size_t)b * 32768, wt_e, w2e, be2, Watt,
                  sRed1, batt[0], sAttW, sNM, adjm + (size_t)blk * 128,
                  node_msg + (size_t)blk * 256);
  // ---- phi_x ----
  egnn_path<false>(tid, sE, sSb, shix, slastx, sqv,
                   hjx + (size_t)b * 32768, wt_x, w2x, bx2, Wx3,
                   sRed2, 0.f, sAttW, sNM, adjm + (size_t)blk * 128,
                   node_msg + (size_t)blk * 256);

  // ---- coord update ----
  if (tid < 128) {
    int j = tid;
    float ea = sRed2[j] + bx3[0];
    float wgt = ea / (sqrtf(sqv[j] + 1e-5f) + 1.0f) * adjm[(size_t)blk * 128 + j];
    float dx = cix - coords[(b * 128 + j) * 3 + 0];
    float dy = ciy - coords[(b * 128 + j) * 3 + 1];
    float dz = ciz - coords[(b * 128 + j) * 3 + 2];
    sRx[j] = wgt * dx; sRy[j] = wgt * dy; sRz[j] = wgt * dz;
  }
  __syncthreads();
  for (int s = 64; s > 0; s >>= 1) {
    if (tid < s) { sRx[tid] += sRx[tid + s]; sRy[tid] += sRy[tid + s]; sRz[tid] += sRz[tid + s]; }
    __syncthreads();
  }
  if (tid < 3) {
    float upd = (tid == 0 ? sRx[0] : (tid == 1 ? sRy[0] : sRz[0])) / (sNum + 1.0f);
    out_coords[blk * 3 + tid] = (coords[blk * 3 + tid] + upd) * amask[blk];
  }
}

// ---------------- h-path + out_feats ----------------
__global__ __launch_bounds__(256) void k_h(
    const float* __restrict__ invf, const float* __restrict__ nmsg,
    const float* __restrict__ Wh1, const float* __restrict__ bh1,
    const float* __restrict__ Wh2, const float* __restrict__ bh2,
    const float* __restrict__ amask, float* __restrict__ out_feats)
{
  __shared__ float sIn[4][512];
  __shared__ float sH1[4][256];
  int c = threadIdx.x;
  int node0 = blockIdx.x * 4;
  #pragma unroll
  for (int nn = 0; nn < 4; nn++) {
    sIn[nn][c] = invf[(node0 + nn) * 256 + c];
    sIn[nn][256 + c] = nmsg[(node0 + nn) * 256 + c];
  }
  __syncthreads();
  float a1[4];
  #pragma unroll
  for (int nn = 0; nn < 4; nn++) a1[nn] = bh1[c];
  #pragma unroll 4
  for (int k = 0; k < 512; k++) {
    float wv = Wh1[k * 256 + c];
    #pragma unroll
    for (int nn = 0; nn < 4; nn++) a1[nn] += sIn[nn][k] * wv;
  }
  #pragma unroll
  for (int nn = 0; nn < 4; nn++) sH1[nn][c] = siluf(a1[nn]);
  __syncthreads();
  float a2[4];
  #pragma unroll
  for (int nn = 0; nn < 4; nn++) a2[nn] = bh2[c];
  #pragma unroll 4
  for (int k = 0; k < 256; k++) {
    float wv = Wh2[k * 256 + c];
    #pragma unroll
    for (int nn = 0; nn < 4; nn++) a2[nn] += sH1[nn][k] * wv;
  }
  #pragma unroll
  for (int nn = 0; nn < 4; nn++)
    out_feats[(node0 + nn) * 256 + c] = a2[nn] * amask[node0 + nn];
}

extern "C" void kernel_launch(void* const* d_in, const int* in_sizes, int n_in,
                              void* d_out, int out_size, void* d_ws, size_t ws_size,
                              hipStream_t stream)
{
  const float* coords = (const float*)d_in[0];
  const float* invf  = (const float*)d_in[1];
  const float* adjm  = (const float*)d_in[2];
  const float* amask = (const float*)d_in[3];
  const float* ef    = (const float*)d_in[4];
  const float* We1   = (const float*)d_in[5];
  const float* be1   = (const float*)d_in[6];
  const float* We2   = (const float*)d_in[7];
  const float* be2   = (const float*)d_in[8];
  const float* Watt  = (const float*)d_in[9];
  const float* batt  = (const float*)d_in[10];
  const float* Wh1   = (const float*)d_in[11];
  const float* bh1   = (const float*)d_in[12];
  const float* Wh2   = (const float*)d_in[13];
  const float* bh2   = (const float*)d_in[14];
  const float* Wx1   = (const float*)d_in[15];
  const float* bx1   = (const float*)d_in[16];
  const float* Wx2   = (const float*)d_in[17];
  const float* bx2   = (const float*)d_in[18];
  const float* Wx3   = (const float*)d_in[19];
  const float* bx3   = (const float*)d_in[20];

  char* ws = (char*)d_ws;
  float* hie  = (float*)(ws + (size_t)0);
  float* hje  = (float*)(ws + (size_t)(1u << 20));
  float* hix  = (float*)(ws + (size_t)(2u << 20));
  float* hjx  = (float*)(ws + (size_t)(3u << 20));
  float* nmsg = (float*)(ws + (size_t)(4u << 20));
  __bf16* wt_e = (__bf16*)(ws + (size_t)(5u << 20));
  __bf16* wt_x = (__bf16*)(ws + (size_t)(5u << 20) + 32768);
  __bf16* w2e  = (__bf16*)(ws + (size_t)(5u << 20) + 65536);
  __bf16* w2x  = (__bf16*)(ws + (size_t)(5u << 20) + 65536 + 131072);

  float* out_coords = (float*)d_out;
  float* out_feats  = out_coords + NB * NNODE * 3;

  hipLaunchKernelGGL(k_prep, dim3(256), dim3(256), 0, stream,
                     We1, Wx1, We2, Wx2, wt_e, wt_x, w2e, w2x);
  hipLaunchKernelGGL(k_nodes, dim3(256), dim3(256), 0, stream,
                     invf, We1, Wx1, be1, bx1, hie, hje, hix, hjx);
  hipLaunchKernelGGL(k_edge, dim3(1024), dim3(512), 0, stream,
                     coords, adjm, amask, ef, We1, Wx1, Watt, batt, be2, bx2, bx3,
                     hie, hje, hix, hjx, wt_e, wt_x, w2e, w2x, Wx3, nmsg, out_coords);
  hipLaunchKernelGGL(k_h, dim3(256), dim3(256), 0, stream,
                     invf, nmsg, Wh1, bh1, Wh2, bh2, amask, out_feats);
}